// Round 14
// baseline (2383.287 us; speedup 1.0000x reference)
//
#include <hip/hip_runtime.h>

// ---------------------------------------------------------------------------
// DepTreeLSTM on MI355X — round 14: FULL tree-local fusion, rolling LDS stash.
// tree_kernel: block = 2 trees (126 nodes), 2048 blocks, 512 thr (8 waves).
// Phases: leaf(64 rows, K=256, NT=3) -> lvl1(32)...lvl5(2) (K=512, NT=5).
// h (bf16) + c (f32) of the PREVIOUS level live in a rolling 64-row LDS
// stash; each phase reads children from it and overwrites it. cbuf HBM is
// GONE; HBM = emb read + hout write only (~400 MB).
// Hazard closure: 2 barriers/phase; epilogue stash access is wave-column-
// owned (hcol in [16w,16w+16)); c reads hoisted before ANY stash write
// (sched_barrier-fenced) to close the row-overwrite race; cross-column
// stash reads only in staging (behind the phase barrier).
// B: fragment-packed BTf streamed into registers (R12/R13 ping-pong).
// LDS: A 32K + hstash 16K + cstash 32K = 80 KB -> 2 blocks/CU.
// ws: BTf bf16 fragment-packed at 0 (655 KB). No other state.
// ---------------------------------------------------------------------------

typedef float f32x4 __attribute__((ext_vector_type(4)));
typedef __bf16 bf16x8 __attribute__((ext_vector_type(8)));
typedef unsigned short u16x8 __attribute__((ext_vector_type(8)));

__device__ __forceinline__ unsigned short f2bf(float x) {
  unsigned int u = __float_as_uint(x);
  return (unsigned short)((u + 0x7fffu + ((u >> 16) & 1u)) >> 16);
}
__device__ __forceinline__ float bf2f(unsigned short u) {
  return __uint_as_float(((unsigned int)u) << 16);
}
__device__ __forceinline__ float sigf(float x) { return 1.f / (1.f + __expf(-x)); }
__device__ __forceinline__ float tanhfast(float x) {
  return 1.f - 2.f / (__expf(2.f * x) + 1.f);
}

// Pack B in fragment order: BTf[((tile*16 + ks)*64 + lane)*8 + j]
// lane = kq*16 + cl, col = tile*16+cl, k = ks*32 + kq*8 + j  (K=512).
// col<384: W_iou/U_iou; col>=384: W_f (dup f0/f1) / U_f_w.
__global__ void prep_kernel(const float* __restrict__ Wi, const float* __restrict__ Ui,
                            const float* __restrict__ Wf, const float* __restrict__ Uf,
                            unsigned short* __restrict__ BTf) {
  int idx = blockIdx.x * 256 + threadIdx.x;
  int j = idx & 7;
  int lane = (idx >> 3) & 63;
  int ks = (idx >> 9) & 15;
  int tile = idx >> 13;
  int cl = lane & 15, kq = lane >> 4;
  int col = tile * 16 + cl;
  int k = ks * 32 + kq * 8 + j;
  float v;
  if (k < 256) {
    v = (col < 384) ? Wi[k * 384 + col] : Wf[k * 128 + ((col - 384) & 127)];
  } else {
    int kk = k & 255;
    v = (col < 384) ? Ui[kk * 384 + col] : Uf[kk * 256 + (col - 384)];
  }
  BTf[idx] = f2bf(v);
}

// A-LDS fragment-order address (elements): ((mt*NKS + ks)*64 + kq*16 + r)*8 + j
template <int NKS>
__device__ __forceinline__ int a_addr(int rblk, int k) {
  int mt = rblk >> 4, r = rblk & 15;
  int ks = k >> 5, kq = (k >> 3) & 3, j = k & 7;
  return (((mt * NKS + ks) * 64 + (kq << 4) + r) << 3) + j;
}

// register ping-pong B-stream GEMM (R12/R13 proven)
template <int MT, int NT, int NKS>
__device__ __forceinline__ void run_gemm_reg(const unsigned short* __restrict__ Bw,
                                             const unsigned short* Alds,
                                             int lane, f32x4 (&acc)[MT][NT]) {
  bf16x8 bA[NT], bB[NT];
#pragma unroll
  for (int t = 0; t < NT; ++t) bA[t] = *(const bf16x8*)&Bw[(size_t)t * 65536];
#pragma unroll
  for (int ks2 = 0; ks2 < NKS / 2; ++ks2) {
#pragma unroll
    for (int half = 0; half < 2; ++half) {
      const int ks = 2 * ks2 + half;
      bf16x8* cur = half ? bB : bA;
      bf16x8* nxt = half ? bA : bB;
      if (ks + 1 < NKS) {
#pragma unroll
        for (int t = 0; t < NT; ++t)
          nxt[t] = *(const bf16x8*)&Bw[(size_t)t * 65536 + (ks + 1) * 512];
      }
      __builtin_amdgcn_s_setprio(1);
#pragma unroll
      for (int mt = 0; mt < MT; ++mt) {
        const bf16x8 a = *(const bf16x8*)&Alds[((mt * NKS + ks) * 64 + lane) << 3];
#pragma unroll
        for (int t = 0; t < NT; ++t)
          acc[mt][t] = __builtin_amdgcn_mfma_f32_16x16x32_bf16(a, cur[t], acc[mt][t], 0, 0, 0);
      }
      __builtin_amdgcn_s_setprio(0);
    }
  }
}

// one internal level: ROWS=2*CNT rows (2 trees), children in stash rows
// i*2*CNT + 2j (+1); writes this level into stash rows i*CNT+j.
template <int CNT, int LCD, int MT>
__device__ __forceinline__ void do_phase(
    int offs, int g0,
    const float* __restrict__ emb, const float* __restrict__ cmask,
    const int* __restrict__ ctype, const unsigned short* __restrict__ Bw,
    const float* __restrict__ b_iou, const float* __restrict__ ufb,
    const float* __restrict__ bf_, float* __restrict__ hout,
    unsigned short* Alds, unsigned short* hstash, float* cstash,
    int tid, int lane, int w) {
  constexpr int ROWS = 2 * CNT;
  // ---- stage emb (k<256): thread owns 8 consecutive k of one row ----
  constexpr int EITER = (ROWS * 32 + 511) / 512;
#pragma unroll
  for (int it = 0; it < EITER; ++it) {
    const int f = it * 512 + tid;
    if (EITER * 512 == ROWS * 32 || f < ROWS * 32) {
      const int rblk = f >> 5, sub = f & 31;
      const int i = rblk >> LCD, j = rblk & (CNT - 1);
      const int g = g0 + i * 63 + offs + j;
      const int k0 = sub * 8;
      const float4 v0 = *(const float4*)&emb[(size_t)g * 256 + k0];
      const float4 v1 = *(const float4*)&emb[(size_t)g * 256 + k0 + 4];
      ushort4 p0, p1;
      p0.x = f2bf(v0.x); p0.y = f2bf(v0.y); p0.z = f2bf(v0.z); p0.w = f2bf(v0.w);
      p1.x = f2bf(v1.x); p1.y = f2bf(v1.y); p1.z = f2bf(v1.z); p1.w = f2bf(v1.w);
      unsigned short* dst = &Alds[a_addr<16>(rblk, k0)];
      *(ushort4*)dst = p0;
      *(ushort4*)(dst + 4) = p1;
    }
  }
  // ---- stage ht0/ht1 (k 256..511) from hstash (16 thr/row, 8 cols) ----
  if (tid < ROWS * 16) {
    const int rblk = tid >> 4, q = tid & 15;
    const int i = rblk >> LCD, j = rblk & (CNT - 1);
    const int gp = g0 + i * 63 + offs + j;
    const int chb = i * 2 * CNT + 2 * j;
    const int ty0 = ctype[2 * gp], ty1 = ctype[2 * gp + 1];
    const float c0 = cmask[2 * gp], c1 = cmask[2 * gp + 1];
    const float w00 = (ty0 == 0) ? c0 : 0.f, w01 = (ty1 == 0) ? c1 : 0.f;
    const float w10 = (ty0 == 1) ? c0 : 0.f, w11 = (ty1 == 1) ? c1 : 0.f;
    const int jc = q * 8;
    const u16x8 va = *(const u16x8*)&hstash[chb * 128 + jc];
    const u16x8 vb = *(const u16x8*)&hstash[(chb + 1) * 128 + jc];
    u16x8 o0, o1;
#pragma unroll
    for (int e = 0; e < 8; ++e) {
      const float fa = bf2f(va[e]), fb = bf2f(vb[e]);
      o0[e] = f2bf(w00 * fa + w01 * fb);
      o1[e] = f2bf(w10 * fa + w11 * fb);
    }
    *(u16x8*)&Alds[a_addr<16>(rblk, 256 + jc)] = o0;
    *(u16x8*)&Alds[a_addr<16>(rblk, 384 + jc)] = o1;
  }
  __syncthreads();

  f32x4 acc[MT][5];
#pragma unroll
  for (int mt = 0; mt < MT; ++mt)
#pragma unroll
    for (int t = 0; t < 5; ++t) acc[mt][t] = (f32x4){0.f, 0.f, 0.f, 0.f};
  run_gemm_reg<MT, 5, 16>(Bw, Alds, lane, acc);

  const int cl = lane & 15;
  const int rb = (lane >> 4) << 2;
  const int hcol = w * 16 + cl;

  // ---- epilogue: hoist ALL child-c reads before ANY stash write ----
  float c0v[MT][4], c1v[MT][4];
#pragma unroll
  for (int mt = 0; mt < MT; ++mt)
#pragma unroll
    for (int r = 0; r < 4; ++r) {
      const int row = (mt << 4) + rb + r;
      c0v[mt][r] = 0.f; c1v[mt][r] = 0.f;
      if (row < ROWS) {
        const int i = row >> LCD, j = row & (CNT - 1);
        const int chb = i * 2 * CNT + 2 * j;
        c0v[mt][r] = cstash[chb * 128 + hcol];
        c1v[mt][r] = cstash[(chb + 1) * 128 + hcol];
      }
    }
  __builtin_amdgcn_sched_barrier(0);   // reads complete before writes below

  const float bi = b_iou[hcol], bo = b_iou[128 + hcol], bu = b_iou[256 + hcol];
  const float f0b = ufb[hcol], f1b = ufb[128 + hcol], bfv = bf_[hcol];
#pragma unroll
  for (int mt = 0; mt < MT; ++mt)
#pragma unroll
    for (int r = 0; r < 4; ++r) {
      const int row = (mt << 4) + rb + r;
      if (row < ROWS) {
        const int i = row >> LCD, j = row & (CNT - 1);
        const int g = g0 + i * 63 + offs + j;
        const int ty0 = ctype[2 * g], ty1 = ctype[2 * g + 1];
        const float cm0 = cmask[2 * g], cm1 = cmask[2 * g + 1];
        const float iv = acc[mt][0][r] + bi;
        const float ov = acc[mt][1][r] + bo;
        const float uv = acc[mt][2][r] + bu;
        const float f0 = acc[mt][3][r] + f0b;
        const float f1 = acc[mt][4][r] + f1b;
        const float fa = (ty0 == 0) ? f0 : f1;
        const float fb = (ty1 == 0) ? f0 : f1;
        const float ft0 = sigf(fa + bfv);
        const float ft1 = sigf(fb + bfv);
        const float ccell = ft0 * c0v[mt][r] * cm0 + ft1 * c1v[mt][r] * cm1;
        const float cn = sigf(iv) * tanhfast(uv) + ccell;
        const float hn = sigf(ov) * tanhfast(cn);
        hout[(size_t)g * 128 + hcol] = hn;
        hstash[row * 128 + hcol] = f2bf(hn);
        cstash[row * 128 + hcol] = cn;
      }
    }
  __syncthreads();   // stash of this level visible to next phase's staging
}

__global__ __launch_bounds__(512, 4) void tree_kernel(
    const float* __restrict__ emb, const float* __restrict__ cmask,
    const int* __restrict__ ctype, const unsigned short* __restrict__ BTf,
    const float* __restrict__ b_iou, const float* __restrict__ ufb,
    const float* __restrict__ bf_, float* __restrict__ hout) {
  __shared__ unsigned short Alds[16384];   // 32 KB
  __shared__ unsigned short hstash[8192];  // 16 KB: 64 rows x 128 bf16
  __shared__ float cstash[8192];           // 32 KB: 64 rows x 128 f32

  const int tid = threadIdx.x;
  const int lane = tid & 63;
  const int w = tid >> 6;
  const int cl = lane & 15;
  const int rb = (lane >> 4) << 2;
  const int hcol = w * 16 + cl;
  const int g0 = blockIdx.x * 126;   // two trees

  const unsigned short* Bw = BTf + (size_t)w * 8192 + lane * 8;

  // ============ leaf phase: 64 rows, K=256, NT=3 ============
#pragma unroll
  for (int c = 0; c < 4; ++c) {
    const int ks_e = tid >> 6;
    const int lq = tid & 63;
    const int k0 = ks_e * 32 + (lq >> 4) * 8;
    const int rblk = c * 16 + (lq & 15);
    const int g = g0 + (rblk >> 5) * 63 + (rblk & 31);
    const float4 v0 = *(const float4*)&emb[(size_t)g * 256 + k0];
    const float4 v1 = *(const float4*)&emb[(size_t)g * 256 + k0 + 4];
    ushort4 p0, p1;
    p0.x = f2bf(v0.x); p0.y = f2bf(v0.y); p0.z = f2bf(v0.z); p0.w = f2bf(v0.w);
    p1.x = f2bf(v1.x); p1.y = f2bf(v1.y); p1.z = f2bf(v1.z); p1.w = f2bf(v1.w);
    unsigned short* dst = &Alds[((c * 8 + ks_e) * 64 + lq) * 8];
    *(ushort4*)dst = p0;
    *(ushort4*)(dst + 4) = p1;
  }
  __syncthreads();
  {
    f32x4 acc[4][3];
#pragma unroll
    for (int mt = 0; mt < 4; ++mt)
#pragma unroll
      for (int t = 0; t < 3; ++t) acc[mt][t] = (f32x4){0.f, 0.f, 0.f, 0.f};
    run_gemm_reg<4, 3, 8>(Bw, Alds, lane, acc);
    const float bi = b_iou[hcol], bo = b_iou[128 + hcol], bu = b_iou[256 + hcol];
#pragma unroll
    for (int mt = 0; mt < 4; ++mt) {
#pragma unroll
      for (int r = 0; r < 4; ++r) {
        const int row = (mt << 4) + rb + r;
        const int g = g0 + (row >> 5) * 63 + (row & 31);
        const float cn = sigf(acc[mt][0][r] + bi) * tanhfast(acc[mt][2][r] + bu);
        const float hn = sigf(acc[mt][1][r] + bo) * tanhfast(cn);
        hout[(size_t)g * 128 + hcol] = hn;
        hstash[row * 128 + hcol] = f2bf(hn);
        cstash[row * 128 + hcol] = cn;
      }
    }
  }
  __syncthreads();

  // ============ internal levels ============
  do_phase<16, 4, 2>(32, g0, emb, cmask, ctype, Bw, b_iou, ufb, bf_, hout,
                     Alds, hstash, cstash, tid, lane, w);
  do_phase<8, 3, 1>(48, g0, emb, cmask, ctype, Bw, b_iou, ufb, bf_, hout,
                    Alds, hstash, cstash, tid, lane, w);
  do_phase<4, 2, 1>(56, g0, emb, cmask, ctype, Bw, b_iou, ufb, bf_, hout,
                    Alds, hstash, cstash, tid, lane, w);
  do_phase<2, 1, 1>(60, g0, emb, cmask, ctype, Bw, b_iou, ufb, bf_, hout,
                    Alds, hstash, cstash, tid, lane, w);
  do_phase<1, 0, 1>(62, g0, emb, cmask, ctype, Bw, b_iou, ufb, bf_, hout,
                    Alds, hstash, cstash, tid, lane, w);
}

extern "C" void kernel_launch(void* const* d_in, const int* in_sizes, int n_in,
                              void* d_out, int out_size, void* d_ws, size_t ws_size,
                              hipStream_t stream) {
  (void)in_sizes; (void)n_in; (void)out_size; (void)ws_size;
  const float* emb   = (const float*)d_in[0];
  const float* cmask = (const float*)d_in[1];
  const float* W_iou = (const float*)d_in[2];
  const float* U_iou = (const float*)d_in[3];
  const float* b_iou = (const float*)d_in[4];
  const float* W_f   = (const float*)d_in[5];
  const float* U_f_w = (const float*)d_in[6];
  const float* U_f_b = (const float*)d_in[7];
  const float* b_f   = (const float*)d_in[8];
  const int* ctype   = (const int*)d_in[10];
  float* hout = (float*)d_out;

  unsigned short* BTf = (unsigned short*)d_ws;   // 655360 B

  prep_kernel<<<1280, 256, 0, stream>>>(W_iou, U_iou, W_f, U_f_w, BTf);
  tree_kernel<<<2048, 512, 0, stream>>>(emb, cmask, ctype, BTf, b_iou,
                                        U_f_b, b_f, hout);
}

// Round 15
// 267.009 us; speedup vs baseline: 8.9259x; 8.9259x over previous
//
#include <hip/hip_runtime.h>

// ---------------------------------------------------------------------------
// DepTreeLSTM on MI355X — round 15: R13 + HW bf16 cvt + spill-safe ping-pong.
// fused_kernel: block = 2 trees (64 leaves + 32 lvl1 nodes), 2048 blocks.
//   Phase 0: leaf GEMM (MT=4, K=256, NT=3) + LSTM epilogue.
//            h -> hout(HBM) + LDS hstash(bf16); c -> LDS cstash(f32) ONLY.
//   Phase 1: lvl1 GEMM (MT=2, K=512, NT=5). ht from hstash, c_cell from
//            cstash. h,c -> HBM.
// Tails lvl2..5: register-ping-pong B stream (R12). All f32->bf16 via HW
// v_cvt (was 4-op manual RNE — VALUBusy was 46%). No pointer selects over
// register arrays anywhere (R14's scratch-spill trigger).
// LDS: A 32K + hstash 16K + cstash 32K = 80 KB -> 2 blocks/CU.
// ws: BTf bf16 fragment-packed at 0; c-state f32 [N][128] at 1MB.
// ---------------------------------------------------------------------------

typedef float f32x4 __attribute__((ext_vector_type(4)));
typedef __bf16 bf16x8 __attribute__((ext_vector_type(8)));
typedef unsigned short u16x8 __attribute__((ext_vector_type(8)));

__device__ __forceinline__ unsigned short f2bf(float x) {
  union { __bf16 b; unsigned short u; } cv;
  cv.b = (__bf16)x;                      // HW v_cvt, RNE — same numerics
  return cv.u;
}
__device__ __forceinline__ float bf2f(unsigned short u) {
  return __uint_as_float(((unsigned int)u) << 16);
}
__device__ __forceinline__ float sigf(float x) { return 1.f / (1.f + __expf(-x)); }
__device__ __forceinline__ float tanhfast(float x) {
  return 1.f - 2.f / (__expf(2.f * x) + 1.f);
}

// Pack B in fragment order: BTf[((tile*16 + ks)*64 + lane)*8 + j]
// lane = kq*16 + cl, col = tile*16+cl, k = ks*32 + kq*8 + j  (K=512).
// col<384: W_iou/U_iou; col>=384: W_f (dup f0/f1) / U_f_w.
__global__ void prep_kernel(const float* __restrict__ Wi, const float* __restrict__ Ui,
                            const float* __restrict__ Wf, const float* __restrict__ Uf,
                            unsigned short* __restrict__ BTf) {
  int idx = blockIdx.x * 256 + threadIdx.x;
  int j = idx & 7;
  int lane = (idx >> 3) & 63;
  int ks = (idx >> 9) & 15;
  int tile = idx >> 13;
  int cl = lane & 15, kq = lane >> 4;
  int col = tile * 16 + cl;
  int k = ks * 32 + kq * 8 + j;
  float v;
  if (k < 256) {
    v = (col < 384) ? Wi[k * 384 + col] : Wf[k * 128 + ((col - 384) & 127)];
  } else {
    int kk = k & 255;
    v = (col < 384) ? Ui[kk * 384 + col] : Uf[kk * 256 + (col - 384)];
  }
  BTf[idx] = f2bf(v);
}

// A-LDS fragment-order address (elements): ((mt*NKS + ks)*64 + kq*16 + r)*8 + j
template <int NKS>
__device__ __forceinline__ int a_addr(int rblk, int k) {
  int mt = rblk >> 4, r = rblk & 15;
  int ks = k >> 5, kq = (k >> 3) & 3, j = k & 7;
  return (((mt * NKS + ks) * 64 + (kq << 4) + r) << 3) + j;
}

// ======================= fused leaf + lvl1 kernel ==========================
__global__ __launch_bounds__(512, 4) void fused_kernel(
    const float* __restrict__ emb, const float* __restrict__ cmask,
    const int* __restrict__ ctype,
    const unsigned short* __restrict__ BTf,
    const float* __restrict__ b_iou, const float* __restrict__ ufb,
    const float* __restrict__ bf_,
    float* __restrict__ hout, float* __restrict__ cbuf) {
  __shared__ unsigned short Alds[16384];   // 32 KB
  __shared__ unsigned short hstash[8192];  // 16 KB: 64 leaves x 128 bf16
  __shared__ float cstash[8192];           // 32 KB: 64 leaves x 128 f32

  const int tid = threadIdx.x;
  const int lane = tid & 63;
  const int w = tid >> 6;
  const int cl = lane & 15;
  const int rb = (lane >> 4) << 2;
  const int hcol = w * 16 + cl;
  const int g0 = blockIdx.x * 126;       // two trees

  const unsigned short* Bw = BTf + (size_t)w * 8192 + lane * 8;

  // ---- Phase 0 staging: 64 leaf emb rows, fragment image (NKS=8) ----
#pragma unroll
  for (int c = 0; c < 4; ++c) {
    const int ks_e = tid >> 6;
    const int lq = tid & 63;
    const int k0 = ks_e * 32 + (lq >> 4) * 8;
    const int rblk = c * 16 + (lq & 15);
    const int g = g0 + (rblk >> 5) * 63 + (rblk & 31);
    const float4 v0 = *(const float4*)&emb[(size_t)g * 256 + k0];
    const float4 v1 = *(const float4*)&emb[(size_t)g * 256 + k0 + 4];
    ushort4 p0, p1;
    p0.x = f2bf(v0.x); p0.y = f2bf(v0.y); p0.z = f2bf(v0.z); p0.w = f2bf(v0.w);
    p1.x = f2bf(v1.x); p1.y = f2bf(v1.y); p1.z = f2bf(v1.z); p1.w = f2bf(v1.w);
    unsigned short* dst = &Alds[((c * 8 + ks_e) * 64 + lq) * 8];
    *(ushort4*)dst = p0;
    *(ushort4*)(dst + 4) = p1;
  }
  __syncthreads();

  // ---- Phase 0 GEMM: MT=4, NT=3, slices 0..7 ----
  {
    f32x4 acc[4][3];
#pragma unroll
    for (int mt = 0; mt < 4; ++mt)
#pragma unroll
      for (int t = 0; t < 3; ++t) acc[mt][t] = (f32x4){0.f, 0.f, 0.f, 0.f};
    bf16x8 bA[3], bB[3];
#pragma unroll
    for (int t = 0; t < 3; ++t) bA[t] = *(const bf16x8*)&Bw[(size_t)t * 65536];
    auto step0 = [&](bf16x8(&cur)[3], bf16x8(&nxt)[3], int ks) {
      if (ks + 1 < 8) {
#pragma unroll
        for (int t = 0; t < 3; ++t)
          nxt[t] = *(const bf16x8*)&Bw[(size_t)t * 65536 + (ks + 1) * 512];
      }
      __builtin_amdgcn_s_setprio(1);
#pragma unroll
      for (int mt = 0; mt < 4; ++mt) {
        const bf16x8 a = *(const bf16x8*)&Alds[((mt * 8 + ks) * 64 + lane) << 3];
#pragma unroll
        for (int t = 0; t < 3; ++t)
          acc[mt][t] = __builtin_amdgcn_mfma_f32_16x16x32_bf16(a, cur[t], acc[mt][t], 0, 0, 0);
      }
      __builtin_amdgcn_s_setprio(0);
    };
#pragma unroll
    for (int ks2 = 0; ks2 < 4; ++ks2) {
      step0(bA, bB, 2 * ks2);
      step0(bB, bA, 2 * ks2 + 1);
    }
    // ---- Phase 0 epilogue: h->hout+hstash, c->cstash only ----
    const float bi = b_iou[hcol], bo = b_iou[128 + hcol], bu = b_iou[256 + hcol];
#pragma unroll
    for (int mt = 0; mt < 4; ++mt) {
#pragma unroll
      for (int r = 0; r < 4; ++r) {
        const int row = (mt << 4) + rb + r;
        const int g = g0 + (row >> 5) * 63 + (row & 31);
        const float cn = sigf(acc[mt][0][r] + bi) * tanhfast(acc[mt][2][r] + bu);
        const float hn = sigf(acc[mt][1][r] + bo) * tanhfast(cn);
        hout[(size_t)g * 128 + hcol] = hn;
        hstash[row * 128 + hcol] = f2bf(hn);
        cstash[row * 128 + hcol] = cn;
      }
    }
  }
  __syncthreads();   // stash visible; Alds free for reuse

  // ---- Phase 1 staging: 32 lvl1 rows, K=512 fragment image (NKS=16) ----
#pragma unroll
  for (int c = 0; c < 2; ++c) {
    const int ks_e = tid >> 6;
    const int lq = tid & 63;
    const int k0 = ks_e * 32 + (lq >> 4) * 8;
    const int rblk = c * 16 + (lq & 15);
    const int g = g0 + (rblk >> 4) * 63 + 32 + (rblk & 15);
    const float4 v0 = *(const float4*)&emb[(size_t)g * 256 + k0];
    const float4 v1 = *(const float4*)&emb[(size_t)g * 256 + k0 + 4];
    ushort4 p0, p1;
    p0.x = f2bf(v0.x); p0.y = f2bf(v0.y); p0.z = f2bf(v0.z); p0.w = f2bf(v0.w);
    p1.x = f2bf(v1.x); p1.y = f2bf(v1.y); p1.z = f2bf(v1.z); p1.w = f2bf(v1.w);
    unsigned short* dst = &Alds[((c * 16 + ks_e) * 64 + lq) * 8];
    *(ushort4*)dst = p0;
    *(ushort4*)(dst + 4) = p1;
  }
  // ht part (k 256..511) from hstash: 16 threads/row, 8 cols each
  {
    const int rblk = tid >> 4, q = tid & 15;
    const int i = rblk >> 4, j = rblk & 15;
    const int gp = g0 + i * 63 + 32 + j;
    const int ch0 = i * 32 + 2 * j, ch1 = ch0 + 1;
    const int ty0 = ctype[2 * gp], ty1 = ctype[2 * gp + 1];
    const float c0 = cmask[2 * gp], c1 = cmask[2 * gp + 1];
    const float w00 = (ty0 == 0) ? c0 : 0.f, w01 = (ty1 == 0) ? c1 : 0.f;
    const float w10 = (ty0 == 1) ? c0 : 0.f, w11 = (ty1 == 1) ? c1 : 0.f;
    const int jc = q * 8;
    const u16x8 va = *(const u16x8*)&hstash[ch0 * 128 + jc];
    const u16x8 vb = *(const u16x8*)&hstash[ch1 * 128 + jc];
    u16x8 o0, o1;
#pragma unroll
    for (int e = 0; e < 8; ++e) {
      const float fa = bf2f(va[e]), fb = bf2f(vb[e]);
      o0[e] = f2bf(w00 * fa + w01 * fb);
      o1[e] = f2bf(w10 * fa + w11 * fb);
    }
    *(u16x8*)&Alds[a_addr<16>(rblk, 256 + jc)] = o0;
    *(u16x8*)&Alds[a_addr<16>(rblk, 384 + jc)] = o1;
  }
  __syncthreads();

  // ---- Phase 1 GEMM: MT=2, NT=5, slices 0..15 ----
  {
    f32x4 acc[2][5];
#pragma unroll
    for (int mt = 0; mt < 2; ++mt)
#pragma unroll
      for (int t = 0; t < 5; ++t) acc[mt][t] = (f32x4){0.f, 0.f, 0.f, 0.f};
    bf16x8 bA[5], bB[5];
#pragma unroll
    for (int t = 0; t < 5; ++t) bA[t] = *(const bf16x8*)&Bw[(size_t)t * 65536];
    auto step1 = [&](bf16x8(&cur)[5], bf16x8(&nxt)[5], int ks) {
      if (ks + 1 < 16) {
#pragma unroll
        for (int t = 0; t < 5; ++t)
          nxt[t] = *(const bf16x8*)&Bw[(size_t)t * 65536 + (ks + 1) * 512];
      }
      __builtin_amdgcn_s_setprio(1);
#pragma unroll
      for (int mt = 0; mt < 2; ++mt) {
        const bf16x8 a = *(const bf16x8*)&Alds[((mt * 16 + ks) * 64 + lane) << 3];
#pragma unroll
        for (int t = 0; t < 5; ++t)
          acc[mt][t] = __builtin_amdgcn_mfma_f32_16x16x32_bf16(a, cur[t], acc[mt][t], 0, 0, 0);
      }
      __builtin_amdgcn_s_setprio(0);
    };
#pragma unroll
    for (int ks2 = 0; ks2 < 8; ++ks2) {
      step1(bA, bB, 2 * ks2);
      step1(bB, bA, 2 * ks2 + 1);
    }
    // ---- Phase 1 epilogue ----
    const float bi = b_iou[hcol], bo = b_iou[128 + hcol], bu = b_iou[256 + hcol];
    const float f0b = ufb[hcol], f1b = ufb[128 + hcol], bfv = bf_[hcol];
#pragma unroll
    for (int mt = 0; mt < 2; ++mt) {
#pragma unroll
      for (int r = 0; r < 4; ++r) {
        const int row = (mt << 4) + rb + r;
        const int i = row >> 4, j = row & 15;
        const int g = g0 + i * 63 + 32 + j;
        const int ch0 = i * 32 + 2 * j, ch1 = ch0 + 1;
        const int ty0 = ctype[2 * g], ty1 = ctype[2 * g + 1];
        const float c0v = cmask[2 * g], c1v = cmask[2 * g + 1];
        const float iv = acc[mt][0][r] + bi;
        const float ov = acc[mt][1][r] + bo;
        const float uv = acc[mt][2][r] + bu;
        const float f0 = acc[mt][3][r] + f0b;
        const float f1 = acc[mt][4][r] + f1b;
        const float fa = (ty0 == 0) ? f0 : f1;
        const float fb = (ty1 == 0) ? f0 : f1;
        const float ft0 = sigf(fa + bfv);
        const float ft1 = sigf(fb + bfv);
        const float ccell = ft0 * cstash[ch0 * 128 + hcol] * c0v +
                            ft1 * cstash[ch1 * 128 + hcol] * c1v;
        const float cn = sigf(iv) * tanhfast(uv) + ccell;
        const float hn = sigf(ov) * tanhfast(cn);
        cbuf[(size_t)g * 128 + hcol] = cn;
        hout[(size_t)g * 128 + hcol] = hn;
      }
    }
  }
}

// ======================= tail levels (R12 verbatim) ========================
template <bool LEAF, int MT, int WPE>
__global__ __launch_bounds__(512, WPE) void lvl_kernel(
    const float* __restrict__ emb, const float* __restrict__ cmask,
    const int* __restrict__ cidx, const int* __restrict__ ctype,
    const unsigned short* __restrict__ BTf,
    const float* __restrict__ b_iou, const float* __restrict__ ufb,
    const float* __restrict__ bf_,
    float* __restrict__ hout, float* __restrict__ cbuf,
    int lc, int cntm1, int offs) {
  constexpr int KD = LEAF ? 256 : 512;
  constexpr int NKS = KD / 32;
  constexpr int NT = LEAF ? 3 : 5;
  constexpr int ROWS = MT * 16;
  __shared__ unsigned short Alds[ROWS * KD];

  const int tid = threadIdx.x;
  const int lane = tid & 63;
  const int w = tid >> 6;
  const int m0 = blockIdx.x * ROWS;

#pragma unroll
  for (int c = 0; c < MT; ++c) {
    const int ks_e = tid >> 6;
    const int lq = tid & 63;
    const int k0 = ks_e * 32 + (lq >> 4) * 8;
    const int rblk = c * 16 + (lq & 15);
    const int m = m0 + rblk;
    const int g = ((m >> lc) * 63) + offs + (m & cntm1);
    const float4 v0 = *(const float4*)&emb[(size_t)g * 256 + k0];
    const float4 v1 = *(const float4*)&emb[(size_t)g * 256 + k0 + 4];
    ushort4 p0, p1;
    p0.x = f2bf(v0.x); p0.y = f2bf(v0.y); p0.z = f2bf(v0.z); p0.w = f2bf(v0.w);
    p1.x = f2bf(v1.x); p1.y = f2bf(v1.y); p1.z = f2bf(v1.z); p1.w = f2bf(v1.w);
    unsigned short* dst = &Alds[((c * NKS + ks_e) * 64 + lq) * 8];
    *(ushort4*)dst = p0;
    *(ushort4*)(dst + 4) = p1;
  }

  if (!LEAF) {
    constexpr int TPR = 512 / ROWS;
    constexpr int CPT = 128 / TPR;
    const int rblk = tid / TPR, q = tid % TPR;
    const int m = m0 + rblk;
    const int g = ((m >> lc) * 63) + offs + (m & cntm1);
    const int ch0 = cidx[2 * g], ch1 = cidx[2 * g + 1];
    const int ty0 = ctype[2 * g], ty1 = ctype[2 * g + 1];
    const float c0 = cmask[2 * g], c1 = cmask[2 * g + 1];
    const float w00 = (ty0 == 0) ? c0 : 0.f, w01 = (ty1 == 0) ? c1 : 0.f;
    const float w10 = (ty0 == 1) ? c0 : 0.f, w11 = (ty1 == 1) ? c1 : 0.f;
#pragma unroll
    for (int jj = 0; jj < CPT / 4; ++jj) {
      const int j = q * CPT + jj * 4;
      float4 a = *(const float4*)&hout[(size_t)ch0 * 128 + j];
      float4 b = *(const float4*)&hout[(size_t)ch1 * 128 + j];
      ushort4 p0, p1;
      p0.x = f2bf(w00 * a.x + w01 * b.x);
      p0.y = f2bf(w00 * a.y + w01 * b.y);
      p0.z = f2bf(w00 * a.z + w01 * b.z);
      p0.w = f2bf(w00 * a.w + w01 * b.w);
      p1.x = f2bf(w10 * a.x + w11 * b.x);
      p1.y = f2bf(w10 * a.y + w11 * b.y);
      p1.z = f2bf(w10 * a.z + w11 * b.z);
      p1.w = f2bf(w10 * a.w + w11 * b.w);
      *(ushort4*)&Alds[a_addr<NKS>(rblk, 256 + j)] = p0;
      *(ushort4*)&Alds[a_addr<NKS>(rblk, 384 + j)] = p1;
    }
  }
  __syncthreads();

  f32x4 acc[MT][NT];
#pragma unroll
  for (int mt = 0; mt < MT; ++mt)
#pragma unroll
    for (int t = 0; t < NT; ++t) acc[mt][t] = (f32x4){0.f, 0.f, 0.f, 0.f};

  const unsigned short* Bw = BTf + (size_t)w * 8192 + lane * 8;
  bf16x8 bA[NT], bB[NT];
#pragma unroll
  for (int t = 0; t < NT; ++t)
    bA[t] = *(const bf16x8*)&Bw[(size_t)t * 65536];

  auto step = [&](bf16x8(&cur)[NT], bf16x8(&nxt)[NT], int ks) {
    if (ks + 1 < NKS) {
#pragma unroll
      for (int t = 0; t < NT; ++t)
        nxt[t] = *(const bf16x8*)&Bw[(size_t)t * 65536 + (ks + 1) * 512];
    }
    __builtin_amdgcn_s_setprio(1);
#pragma unroll
    for (int mt = 0; mt < MT; ++mt) {
      const bf16x8 a = *(const bf16x8*)&Alds[((mt * NKS + ks) * 64 + lane) << 3];
#pragma unroll
      for (int t = 0; t < NT; ++t)
        acc[mt][t] = __builtin_amdgcn_mfma_f32_16x16x32_bf16(a, cur[t], acc[mt][t], 0, 0, 0);
    }
    __builtin_amdgcn_s_setprio(0);
  };
#pragma unroll
  for (int ks2 = 0; ks2 < NKS / 2; ++ks2) {
    step(bA, bB, 2 * ks2);
    step(bB, bA, 2 * ks2 + 1);
  }

  const int cl = lane & 15;
  const int rb = (lane >> 4) << 2;
  const int hcol = w * 16 + cl;
  const float bi = b_iou[hcol];
  const float bo = b_iou[128 + hcol];
  const float bu = b_iou[256 + hcol];
  float f0b = 0.f, f1b = 0.f, bfv = 0.f;
  if (!LEAF) { f0b = ufb[hcol]; f1b = ufb[128 + hcol]; bfv = bf_[hcol]; }

#pragma unroll
  for (int mt = 0; mt < MT; ++mt) {
#pragma unroll
    for (int r = 0; r < 4; ++r) {
      const int m = m0 + (mt << 4) + rb + r;
      const int g = ((m >> lc) * 63) + offs + (m & cntm1);
      const float iv = acc[mt][0][r] + bi;
      const float ov = acc[mt][1][r] + bo;
      const float uv = acc[mt][2][r] + bu;
      float cn;
      if (LEAF) {
        cn = sigf(iv) * tanhfast(uv);
      } else {
        const int ch0 = cidx[2 * g], ch1 = cidx[2 * g + 1];
        const int ty0 = ctype[2 * g], ty1 = ctype[2 * g + 1];
        const float c0v = cmask[2 * g], c1v = cmask[2 * g + 1];
        const float f0 = acc[mt][3][r] + f0b;
        const float f1 = acc[mt][4][r] + f1b;
        const float fa = (ty0 == 0) ? f0 : f1;
        const float fb = (ty1 == 0) ? f0 : f1;
        const float ft0 = sigf(fa + bfv);
        const float ft1 = sigf(fb + bfv);
        const float ccell = ft0 * cbuf[(size_t)ch0 * 128 + hcol] * c0v +
                            ft1 * cbuf[(size_t)ch1 * 128 + hcol] * c1v;
        cn = sigf(iv) * tanhfast(uv) + ccell;
      }
      const float hn = sigf(ov) * tanhfast(cn);
      cbuf[(size_t)g * 128 + hcol] = cn;
      hout[(size_t)g * 128 + hcol] = hn;
    }
  }
}

extern "C" void kernel_launch(void* const* d_in, const int* in_sizes, int n_in,
                              void* d_out, int out_size, void* d_ws, size_t ws_size,
                              hipStream_t stream) {
  (void)in_sizes; (void)n_in; (void)out_size; (void)ws_size;
  const float* emb   = (const float*)d_in[0];
  const float* cmask = (const float*)d_in[1];
  const float* W_iou = (const float*)d_in[2];
  const float* U_iou = (const float*)d_in[3];
  const float* b_iou = (const float*)d_in[4];
  const float* W_f   = (const float*)d_in[5];
  const float* U_f_w = (const float*)d_in[6];
  const float* U_f_b = (const float*)d_in[7];
  const float* b_f   = (const float*)d_in[8];
  const int* cidx    = (const int*)d_in[9];
  const int* ctype   = (const int*)d_in[10];
  float* hout = (float*)d_out;

  unsigned short* BTf = (unsigned short*)d_ws;                // 655360 B
  float* cbuf = (float*)((char*)d_ws + (size_t)(1 << 20));    // N*128*4 = 132 MB

  prep_kernel<<<1280, 256, 0, stream>>>(W_iou, U_iou, W_f, U_f_w, BTf);

  // leaf + lvl1 fused: 2 trees per block
  fused_kernel<<<2048, 512, 0, stream>>>(emb, cmask, ctype, BTf, b_iou,
                                         U_f_b, b_f, hout, cbuf);
  // levels 2..5
  lvl_kernel<false, 2, 4><<<1024, 512, 0, stream>>>(emb, cmask, cidx, ctype, BTf, b_iou,
                                                    U_f_b, b_f, hout, cbuf, 3, 7, 48);
  lvl_kernel<false, 2, 4><<<512, 512, 0, stream>>>(emb, cmask, cidx, ctype, BTf, b_iou,
                                                   U_f_b, b_f, hout, cbuf, 2, 3, 56);
  lvl_kernel<false, 1, 4><<<512, 512, 0, stream>>>(emb, cmask, cidx, ctype, BTf, b_iou,
                                                   U_f_b, b_f, hout, cbuf, 1, 1, 60);
  lvl_kernel<false, 1, 4><<<256, 512, 0, stream>>>(emb, cmask, cidx, ctype, BTf, b_iou,
                                                   U_f_b, b_f, hout, cbuf, 0, 0, 62);
}